// Round 2
// baseline (145.019 us; speedup 1.0000x reference)
//
#include <hip/hip_runtime.h>
#include <cstdint>
#include <cstddef>

typedef __bf16 bf16x8 __attribute__((ext_vector_type(8)));
typedef float f32x4 __attribute__((ext_vector_type(4)));

#define MFMA16(a, b, c) __builtin_amdgcn_mfma_f32_16x16x32_bf16(a, b, c, 0, 0, 0)

static __device__ __forceinline__ bf16x8 ld_bf16x8(const __bf16* p) {
    return *reinterpret_cast<const bf16x8*>(p);
}

static __device__ __forceinline__ void async_cp16(const __bf16* g, __bf16* l) {
    __builtin_amdgcn_global_load_lds((const __attribute__((address_space(1))) void*)g,
                                     (__attribute__((address_space(3))) void*)l, 16, 0, 0);
}

// ---------------- f32 -> bf16 convert (8 elems/thread) ----------------
__global__ void cvt_kernel(const float* __restrict__ src, __bf16* __restrict__ dst, int n8) {
    int i = blockIdx.x * blockDim.x + threadIdx.x;
    if (i >= n8) return;
    const float4* s4 = reinterpret_cast<const float4*>(src) + (size_t)i * 2;
    float4 a = s4[0], b = s4[1];
    bf16x8 o;
    o[0] = (__bf16)a.x; o[1] = (__bf16)a.y; o[2] = (__bf16)a.z; o[3] = (__bf16)a.w;
    o[4] = (__bf16)b.x; o[5] = (__bf16)b.y; o[6] = (__bf16)b.z; o[7] = (__bf16)b.w;
    reinterpret_cast<bf16x8*>(dst)[i] = o;
}

// ---------------- transpose-convert: in [K][N] f32 -> out [N][K] bf16, 64x64 tiles ----------------
__global__ __launch_bounds__(256) void tcvt_kernel(const float* __restrict__ in,
                                                   __bf16* __restrict__ out, int K, int N) {
    __shared__ __bf16 T[64][72];  // row stride 144B (16B-aligned)
    const int k0 = blockIdx.y * 64, n0 = blockIdx.x * 64;
    const int t = threadIdx.x;
    const int col = (t & 15) << 2;  // n within tile, step 4
    const int rowb = t >> 4;        // k within tile, 0..15
    #pragma unroll
    for (int i = 0; i < 4; i++) {
        int row = i * 16 + rowb;
        float4 v = *reinterpret_cast<const float4*>(&in[(size_t)(k0 + row) * N + n0 + col]);
        T[col + 0][row] = (__bf16)v.x;
        T[col + 1][row] = (__bf16)v.y;
        T[col + 2][row] = (__bf16)v.z;
        T[col + 3][row] = (__bf16)v.w;
    }
    __syncthreads();
    const int oc = (t & 7) << 3;  // k within tile, step 8
    const int orb = t >> 3;       // n within tile, 0..31
    #pragma unroll
    for (int i = 0; i < 2; i++) {
        int r = i * 32 + orb;
        bf16x8 v = *reinterpret_cast<bf16x8*>(&T[r][oc]);
        *reinterpret_cast<bf16x8*>(&out[(size_t)(n0 + r) * K + k0 + oc]) = v;
    }
}

// ---------------- m97-style mainloop: C(128x128) += A(128xK) * Bt(128xK)^T ----------------
// A: [M][K] bf16 row-major. Bt: [N][K] bf16 row-major (pre-transposed weights).
// LDS: linear [128][32] per matrix, staged via global_load_lds width=16.
__device__ __forceinline__ void gemm_mainloop(const __bf16* __restrict__ A,
                                              const __bf16* __restrict__ Bt,
                                              int K, int row0, int col0,
                                              __bf16* Als, __bf16* Bls, f32x4 acc[4][4]) {
    const int tid = threadIdx.x;
    const int lane = tid & 63;
    const int wid = tid >> 6;
    const int wr = wid >> 1, wc = wid & 1;
    // staging: chunk c covers row c/4, k-offset (c%4)*8 (16B). c0 = tid, c1 = tid+256.
    const int r0 = tid >> 2, o0 = (tid & 3) << 3;
    const int r1 = (tid + 256) >> 2, o1 = (tid & 3) << 3;  // (tid+256)&3 == tid&3
    const __bf16* a0 = A + (size_t)(row0 + r0) * K + o0;
    const __bf16* a1 = A + (size_t)(row0 + r1) * K + o1;
    const __bf16* b0 = Bt + (size_t)(col0 + r0) * K + o0;
    const __bf16* b1 = Bt + (size_t)(col0 + r1) * K + o1;
    __bf16* la0 = Als + tid * 8;
    __bf16* la1 = Als + (tid + 256) * 8;
    __bf16* lb0 = Bls + tid * 8;
    __bf16* lb1 = Bls + (tid + 256) * 8;
    // fragment read offsets (bf16 elements) in [128][32] layout
    const int aoff = (wr * 64 + (lane & 15)) * 32 + ((lane >> 4) << 3);
    const int boff = (wc * 64 + (lane & 15)) * 32 + ((lane >> 4) << 3);

    for (int k0 = 0; k0 < K; k0 += 32) {
        async_cp16(a0 + k0, la0);
        async_cp16(a1 + k0, la1);
        async_cp16(b0 + k0, lb0);
        async_cp16(b1 + k0, lb1);
        __syncthreads();  // compiler emits vmcnt(0) drain before barrier
        bf16x8 af[4], bfr[4];
        #pragma unroll
        for (int m = 0; m < 4; m++) af[m] = ld_bf16x8(&Als[aoff + m * 16 * 32]);
        #pragma unroll
        for (int n = 0; n < 4; n++) bfr[n] = ld_bf16x8(&Bls[boff + n * 16 * 32]);
        #pragma unroll
        for (int m = 0; m < 4; m++) {
            #pragma unroll
            for (int n = 0; n < 4; n++) {
                acc[m][n] = MFMA16(af[m], bfr[n], acc[m][n]);
            }
        }
        __syncthreads();
    }
}

// ---------------- QKV GEMM: x(4096x1024) @ w_attn^T(3072x1024) + b_attn ----------------
__global__ __launch_bounds__(256) void gemm_qkv_kernel(const __bf16* __restrict__ xb,
                                                       const __bf16* __restrict__ wabt,
                                                       const float* __restrict__ bias,
                                                       __bf16* __restrict__ qb,
                                                       __bf16* __restrict__ kb,
                                                       __bf16* __restrict__ vt,
                                                       float* __restrict__ present) {
    __shared__ __bf16 Als[128 * 32];
    __shared__ __bf16 Bls[128 * 32];
    f32x4 acc[4][4] = {};
    const int row0 = blockIdx.y * 128, col0 = blockIdx.x * 128;
    gemm_mainloop(xb, wabt, 1024, row0, col0, Als, Bls, acc);

    const int lane = threadIdx.x & 63, wid = threadIdx.x >> 6;
    const int wr = wid >> 1, wc = wid & 1;
    const int part = col0 >> 10;  // uniform per block: 0=q 1=k 2=v
    #pragma unroll
    for (int n = 0; n < 4; n++) {
        int col = col0 + wc * 64 + n * 16 + (lane & 15);
        int hh = (col >> 6) & 15;  // head
        int dd = col & 63;         // dim within head
        float bv = bias[col];
        #pragma unroll
        for (int m = 0; m < 4; m++) {
            #pragma unroll
            for (int r = 0; r < 4; r++) {
                int row = row0 + wr * 64 + m * 16 + ((lane >> 4) << 2) + r;
                int bb = row >> 11, ss = row & 2047;
                float val = acc[m][n][r] + bv;
                size_t qi = (((size_t)(bb * 16 + hh)) * 2048 + ss) * 64 + dd;
                if (part == 0) {
                    qb[qi] = (__bf16)val;
                } else if (part == 1) {
                    kb[qi] = (__bf16)val;
                    present[(((size_t)((bb * 2 + 0) * 16 + hh)) * 2048 + ss) * 64 + dd] = val;
                } else {
                    // transposed V: vt[(bh*64 + d)*2048 + s]
                    vt[(((size_t)(bb * 16 + hh)) * 64 + dd) * 2048 + ss] = (__bf16)val;
                    present[(((size_t)((bb * 2 + 1) * 16 + hh)) * 2048 + ss) * 64 + dd] = val;
                }
            }
        }
    }
}

// ---------------- Proj GEMM: a(4096x1024) @ w_proj^T(1024x1024) + b_proj ----------------
__global__ __launch_bounds__(256) void gemm_proj_kernel(const __bf16* __restrict__ ab,
                                                        const __bf16* __restrict__ wpbt,
                                                        const float* __restrict__ bias,
                                                        float* __restrict__ out) {
    __shared__ __bf16 Als[128 * 32];
    __shared__ __bf16 Bls[128 * 32];
    f32x4 acc[4][4] = {};
    const int row0 = blockIdx.y * 128, col0 = blockIdx.x * 128;
    gemm_mainloop(ab, wpbt, 1024, row0, col0, Als, Bls, acc);

    const int lane = threadIdx.x & 63, wid = threadIdx.x >> 6;
    const int wr = wid >> 1, wc = wid & 1;
    #pragma unroll
    for (int n = 0; n < 4; n++) {
        int col = col0 + wc * 64 + n * 16 + (lane & 15);
        float bv = bias[col];
        #pragma unroll
        for (int m = 0; m < 4; m++) {
            #pragma unroll
            for (int r = 0; r < 4; r++) {
                int row = row0 + wr * 64 + m * 16 + ((lane >> 4) << 2) + r;
                out[(size_t)row * 1024 + col] = acc[m][n][r] + bv;
            }
        }
    }
}

// ---------------- sliding-window causal flash attention ----------------
// grid: (B*H) * (S/64) blocks, 256 threads (4 waves, each wave owns 16 query rows)
__global__ __launch_bounds__(256) void attn_kernel(const __bf16* __restrict__ qb,
                                                   const __bf16* __restrict__ kb,
                                                   const __bf16* __restrict__ vtb,
                                                   __bf16* __restrict__ ab) {
    __shared__ __bf16 Pls[4][16 * 40];  // per-wave P tile [16 q][32 k], padded to 40
    const int bh = blockIdx.x >> 5;     // b*16 + h
    const int qt = blockIdx.x & 31;
    const int lane = threadIdx.x & 63, wid = threadIdx.x >> 6;
    const int q0w = qt * 64 + wid * 16;

    const __bf16* Qh = qb + (size_t)bh * 2048 * 64;
    const __bf16* Kh = kb + (size_t)bh * 2048 * 64;
    const __bf16* Vt = vtb + (size_t)bh * 64 * 2048;
    __bf16* Pw = &Pls[wid][0];

    // load Q fragments (16 rows x 64 d) once
    bf16x8 qf[2];
    {
        int qr = q0w + (lane & 15);
        const __bf16* qp = Qh + (size_t)qr * 64 + ((lane >> 4) << 3);
        qf[0] = ld_bf16x8(qp);
        qf[1] = ld_bf16x8(qp + 32);
    }

    f32x4 o[4];
    #pragma unroll
    for (int dt = 0; dt < 4; dt++) o[dt] = (f32x4){0.f, 0.f, 0.f, 0.f};
    float mrun[4] = {-1e30f, -1e30f, -1e30f, -1e30f};
    float srun[4] = {0.f, 0.f, 0.f, 0.f};

    const float scale = 0.125f;  // 1/sqrt(64)
    int klo = q0w - 255;
    int kt0 = klo > 0 ? (klo & ~31) : 0;

    for (int kt = kt0; kt <= q0w + 15; kt += 32) {
        // ---- scores for 32 keys (two 16-key subtiles) ----
        f32x4 s[2];
        #pragma unroll
        for (int kc = 0; kc < 2; kc++) {
            int krow = kt + kc * 16 + (lane & 15);
            const __bf16* kp = Kh + (size_t)krow * 64 + ((lane >> 4) << 3);
            bf16x8 kf0 = ld_bf16x8(kp);
            bf16x8 kf1 = ld_bf16x8(kp + 32);
            f32x4 a = (f32x4){0.f, 0.f, 0.f, 0.f};
            a = MFMA16(qf[0], kf0, a);
            a = MFMA16(qf[1], kf1, a);
            s[kc] = a;
        }
        // ---- joint online softmax over the 32 keys ----
        float p0v[4], p1v[4], factor[4];
        #pragma unroll
        for (int r = 0; r < 4; r++) {
            int q = q0w + ((lane >> 4) << 2) + r;
            int k0i = kt + (lane & 15);
            int k1i = k0i + 16;
            bool ok0 = (k0i <= q) && (k0i > q - 256);
            bool ok1 = (k1i <= q) && (k1i > q - 256);
            float s0 = ok0 ? s[0][r] * scale : -1e30f;
            float s1 = ok1 ? s[1][r] * scale : -1e30f;
            float mx = fmaxf(s0, s1);
            #pragma unroll
            for (int off = 1; off < 16; off <<= 1) mx = fmaxf(mx, __shfl_xor(mx, off));
            float mn = fmaxf(mrun[r], mx);
            float f = __expf(mrun[r] - mn);
            float p0 = ok0 ? __expf(s0 - mn) : 0.f;
            float p1 = ok1 ? __expf(s1 - mn) : 0.f;
            float ps = p0 + p1;
            #pragma unroll
            for (int off = 1; off < 16; off <<= 1) ps += __shfl_xor(ps, off);
            srun[r] = srun[r] * f + ps;
            mrun[r] = mn;
            factor[r] = f;
            p0v[r] = p0;
            p1v[r] = p1;
        }
        #pragma unroll
        for (int dt = 0; dt < 4; dt++) {
            #pragma unroll
            for (int r = 0; r < 4; r++) o[dt][r] *= factor[r];
        }
        // ---- write P (bf16) to per-wave LDS, [q][key] with pad 40 ----
        #pragma unroll
        for (int r = 0; r < 4; r++) {
            int qrow = ((lane >> 4) << 2) + r;
            Pw[qrow * 40 + (lane & 15)] = (__bf16)p0v[r];
            Pw[qrow * 40 + 16 + (lane & 15)] = (__bf16)p1v[r];
        }
        asm volatile("s_waitcnt lgkmcnt(0)" ::: "memory");
        // ---- PV: o(16x64) += P(16x32) * V(32x64), V from transposed buffer ----
        bf16x8 pf = ld_bf16x8(&Pw[(lane & 15) * 40 + ((lane >> 4) << 3)]);
        #pragma unroll
        for (int dt = 0; dt < 4; dt++) {
            bf16x8 vf = ld_bf16x8(&Vt[(size_t)(dt * 16 + (lane & 15)) * 2048 + kt + ((lane >> 4) << 3)]);
            o[dt] = MFMA16(pf, vf, o[dt]);
        }
    }

    // ---- normalize and store to a_buf [B*S][1024] at head offset ----
    const int bb = bh >> 4, hh = bh & 15;
    #pragma unroll
    for (int r = 0; r < 4; r++) {
        int q = q0w + ((lane >> 4) << 2) + r;
        float inv = 1.f / srun[r];
        size_t base = ((size_t)bb * 2048 + q) * 1024 + hh * 64;
        #pragma unroll
        for (int dt = 0; dt < 4; dt++) {
            ab[base + dt * 16 + (lane & 15)] = (__bf16)(o[dt][r] * inv);
        }
    }
}

// ---------------- launch ----------------
extern "C" void kernel_launch(void* const* d_in, const int* in_sizes, int n_in,
                              void* d_out, int out_size, void* d_ws, size_t ws_size,
                              hipStream_t stream) {
    const float* x = (const float*)d_in[0];       // [2,2048,1024]
    const float* w_attn = (const float*)d_in[1];  // [1024,3072]
    const float* b_attn = (const float*)d_in[2];  // [3072]
    const float* w_proj = (const float*)d_in[3];  // [1024,1024]
    const float* b_proj = (const float*)d_in[4];  // [1024]

    float* out = (float*)d_out;                      // [2,2048,1024]
    float* present = out + (size_t)2 * 2048 * 1024;  // [2,2,16,2048,64]

    char* w = (char*)d_ws;
    __bf16* xb   = (__bf16*)(w);                  // 8 MB (reused as a_buf)
    __bf16* wabt = (__bf16*)(w + 8388608);        // 6 MB  [3072][1024]
    __bf16* wpbt = (__bf16*)(w + 14680064);       // 2 MB  [1024][1024]
    __bf16* qb   = (__bf16*)(w + 16777216);       // 8 MB
    __bf16* kb   = (__bf16*)(w + 25165824);       // 8 MB
    __bf16* vt   = (__bf16*)(w + 33554432);       // 8 MB  [B*H][64][2048] transposed V
    __bf16* ab   = xb;  // a_buf reuses xb region (x consumed before attention writes)

    // converts + weight transposes
    cvt_kernel<<<2048, 256, 0, stream>>>(x, xb, 524288);
    tcvt_kernel<<<dim3(48, 16), 256, 0, stream>>>(w_attn, wabt, 1024, 3072);
    tcvt_kernel<<<dim3(16, 16), 256, 0, stream>>>(w_proj, wpbt, 1024, 1024);

    // QKV projection
    gemm_qkv_kernel<<<dim3(24, 32), 256, 0, stream>>>(xb, wabt, b_attn, qb, kb, vt, present);

    // attention
    attn_kernel<<<1024, 256, 0, stream>>>(qb, kb, vt, ab);

    // output projection
    gemm_proj_kernel<<<dim3(8, 32), 256, 0, stream>>>(ab, wpbt, b_proj, out);
}

// Round 3
// 129.142 us; speedup vs baseline: 1.1229x; 1.1229x over previous
//
#include <hip/hip_runtime.h>
#include <cstdint>
#include <cstddef>

typedef __bf16 bf16x8 __attribute__((ext_vector_type(8)));
typedef float f32x4 __attribute__((ext_vector_type(4)));

#define MFMA16(a, b, c) __builtin_amdgcn_mfma_f32_16x16x32_bf16(a, b, c, 0, 0, 0)

static __device__ __forceinline__ bf16x8 ld_bf16x8(const __bf16* p) {
    return *reinterpret_cast<const bf16x8*>(p);
}

static __device__ __forceinline__ void async_cp16(const __bf16* g, __bf16* l) {
    __builtin_amdgcn_global_load_lds((const __attribute__((address_space(1))) void*)g,
                                     (__attribute__((address_space(3))) void*)l, 16, 0, 0);
}

// ---------------- f32 -> bf16 convert (8 elems/thread) ----------------
__global__ void cvt_kernel(const float* __restrict__ src, __bf16* __restrict__ dst, int n8) {
    int i = blockIdx.x * blockDim.x + threadIdx.x;
    if (i >= n8) return;
    const float4* s4 = reinterpret_cast<const float4*>(src) + (size_t)i * 2;
    float4 a = s4[0], b = s4[1];
    bf16x8 o;
    o[0] = (__bf16)a.x; o[1] = (__bf16)a.y; o[2] = (__bf16)a.z; o[3] = (__bf16)a.w;
    o[4] = (__bf16)b.x; o[5] = (__bf16)b.y; o[6] = (__bf16)b.z; o[7] = (__bf16)b.w;
    reinterpret_cast<bf16x8*>(dst)[i] = o;
}

// ---------------- transpose-convert: in [K][N] f32 -> out [N][K] bf16, 64x64 tiles ----------------
__global__ __launch_bounds__(256) void tcvt_kernel(const float* __restrict__ in,
                                                   __bf16* __restrict__ out, int K, int N) {
    __shared__ __bf16 T[64][72];  // row stride 144B (16B-aligned)
    const int k0 = blockIdx.y * 64, n0 = blockIdx.x * 64;
    const int t = threadIdx.x;
    const int col = (t & 15) << 2;  // n within tile, step 4
    const int rowb = t >> 4;        // k within tile, 0..15
    #pragma unroll
    for (int i = 0; i < 4; i++) {
        int row = i * 16 + rowb;
        float4 v = *reinterpret_cast<const float4*>(&in[(size_t)(k0 + row) * N + n0 + col]);
        T[col + 0][row] = (__bf16)v.x;
        T[col + 1][row] = (__bf16)v.y;
        T[col + 2][row] = (__bf16)v.z;
        T[col + 3][row] = (__bf16)v.w;
    }
    __syncthreads();
    const int oc = (t & 7) << 3;  // k within tile, step 8
    const int orb = t >> 3;       // n within tile, 0..31
    #pragma unroll
    for (int i = 0; i < 2; i++) {
        int r = i * 32 + orb;
        bf16x8 v = *reinterpret_cast<bf16x8*>(&T[r][oc]);
        *reinterpret_cast<bf16x8*>(&out[(size_t)(n0 + r) * K + k0 + oc]) = v;
    }
}

// ---------------- 2-phase double-buffered mainloop: C(128x128) += A(128xK) * Bt(128xK)^T ----
// A: [M][K] bf16 row-major. Bt: [N][K] bf16 row-major (pre-transposed weights).
// T3-minimum recipe: STAGE(t+1) issued BEFORE compute(t); one vmcnt(0)+barrier per K-step.
__device__ __forceinline__ void gemm_mainloop(const __bf16* __restrict__ A,
                                              const __bf16* __restrict__ Bt,
                                              int K, int row0, int col0,
                                              __bf16* Als, __bf16* Bls, f32x4 acc[4][4]) {
    const int tid = threadIdx.x;
    const int lane = tid & 63;
    const int wid = tid >> 6;
    const int wr = wid >> 1, wc = wid & 1;
    // staging: thread covers row tid/4, 16B chunk at k-offset (tid%4)*8; second chunk +64 rows
    const int r0 = tid >> 2, o0 = (tid & 3) << 3;
    const __bf16* a0 = A + (size_t)(row0 + r0) * K + o0;
    const __bf16* a1 = A + (size_t)(row0 + r0 + 64) * K + o0;
    const __bf16* b0 = Bt + (size_t)(col0 + r0) * K + o0;
    const __bf16* b1 = Bt + (size_t)(col0 + r0 + 64) * K + o0;
    const int loff = tid * 8;  // contiguous per-lane LDS dest (global_load_lds requirement)
    // fragment read offsets (bf16 elements) in [128][32] layout
    const int aoff = (wr * 64 + (lane & 15)) * 32 + ((lane >> 4) << 3);
    const int boff = (wc * 64 + (lane & 15)) * 32 + ((lane >> 4) << 3);

    const int nt = K >> 5;
    // prologue: stage tile 0 into buffer 0
    async_cp16(a0, &Als[loff]);
    async_cp16(a1, &Als[loff + 2048]);
    async_cp16(b0, &Bls[loff]);
    async_cp16(b1, &Bls[loff + 2048]);
    __syncthreads();

    int cur = 0;
    for (int t = 0; t < nt; ++t) {
        if (t + 1 < nt) {
            const int k1 = (t + 1) << 5;
            const int nb = (cur ^ 1) * 4096;
            async_cp16(a0 + k1, &Als[nb + loff]);
            async_cp16(a1 + k1, &Als[nb + loff + 2048]);
            async_cp16(b0 + k1, &Bls[nb + loff]);
            async_cp16(b1 + k1, &Bls[nb + loff + 2048]);
        }
        const int cb = cur * 4096;
        bf16x8 af[4], bfr[4];
        #pragma unroll
        for (int m = 0; m < 4; m++) af[m] = ld_bf16x8(&Als[cb + aoff + m * 512]);
        #pragma unroll
        for (int n = 0; n < 4; n++) bfr[n] = ld_bf16x8(&Bls[cb + boff + n * 512]);
        #pragma unroll
        for (int m = 0; m < 4; m++) {
            #pragma unroll
            for (int n = 0; n < 4; n++) {
                acc[m][n] = MFMA16(af[m], bfr[n], acc[m][n]);
            }
        }
        __syncthreads();  // drains vmcnt(0)+lgkmcnt(0): next tile landed, this tile's reads done
        cur ^= 1;
    }
}

// ---------------- QKV GEMM: x(4096x1024) @ w_attn^T(3072x1024) + b_attn ----------------
__global__ __launch_bounds__(256) void gemm_qkv_kernel(const __bf16* __restrict__ xb,
                                                       const __bf16* __restrict__ wabt,
                                                       const float* __restrict__ bias,
                                                       __bf16* __restrict__ qb,
                                                       __bf16* __restrict__ kb,
                                                       __bf16* __restrict__ vt,
                                                       float* __restrict__ present) {
    __shared__ __bf16 Als[2 * 128 * 32];
    __shared__ __bf16 Bls[2 * 128 * 32];
    f32x4 acc[4][4] = {};
    const int row0 = blockIdx.y * 128, col0 = blockIdx.x * 128;
    gemm_mainloop(xb, wabt, 1024, row0, col0, Als, Bls, acc);

    const int lane = threadIdx.x & 63, wid = threadIdx.x >> 6;
    const int wr = wid >> 1, wc = wid & 1;
    const int part = col0 >> 10;  // uniform per block: 0=q 1=k 2=v
    #pragma unroll
    for (int n = 0; n < 4; n++) {
        int col = col0 + wc * 64 + n * 16 + (lane & 15);
        int hh = (col >> 6) & 15;  // head
        int dd = col & 63;         // dim within head
        float bv = bias[col];
        #pragma unroll
        for (int m = 0; m < 4; m++) {
            #pragma unroll
            for (int r = 0; r < 4; r++) {
                int row = row0 + wr * 64 + m * 16 + ((lane >> 4) << 2) + r;
                int bb = row >> 11, ss = row & 2047;
                float val = acc[m][n][r] + bv;
                size_t qi = (((size_t)(bb * 16 + hh)) * 2048 + ss) * 64 + dd;
                if (part == 0) {
                    qb[qi] = (__bf16)val;
                } else if (part == 1) {
                    kb[qi] = (__bf16)val;
                    present[(((size_t)((bb * 2 + 0) * 16 + hh)) * 2048 + ss) * 64 + dd] = val;
                } else {
                    // transposed V: vt[(bh*64 + d)*2048 + s]
                    vt[(((size_t)(bb * 16 + hh)) * 64 + dd) * 2048 + ss] = (__bf16)val;
                    present[(((size_t)((bb * 2 + 1) * 16 + hh)) * 2048 + ss) * 64 + dd] = val;
                }
            }
        }
    }
}

// ---------------- Proj GEMM: a(4096x1024) @ w_proj^T(1024x1024) + b_proj ----------------
__global__ __launch_bounds__(256) void gemm_proj_kernel(const __bf16* __restrict__ ab,
                                                        const __bf16* __restrict__ wpbt,
                                                        const float* __restrict__ bias,
                                                        float* __restrict__ out) {
    __shared__ __bf16 Als[2 * 128 * 32];
    __shared__ __bf16 Bls[2 * 128 * 32];
    f32x4 acc[4][4] = {};
    const int row0 = blockIdx.y * 128, col0 = blockIdx.x * 128;
    gemm_mainloop(ab, wpbt, 1024, row0, col0, Als, Bls, acc);

    const int lane = threadIdx.x & 63, wid = threadIdx.x >> 6;
    const int wr = wid >> 1, wc = wid & 1;
    #pragma unroll
    for (int n = 0; n < 4; n++) {
        int col = col0 + wc * 64 + n * 16 + (lane & 15);
        float bv = bias[col];
        #pragma unroll
        for (int m = 0; m < 4; m++) {
            #pragma unroll
            for (int r = 0; r < 4; r++) {
                int row = row0 + wr * 64 + m * 16 + ((lane >> 4) << 2) + r;
                out[(size_t)row * 1024 + col] = acc[m][n][r] + bv;
            }
        }
    }
}

// ---------------- sliding-window causal flash attention ----------------
// grid: (B*H) * (S/64) blocks, 256 threads (4 waves, each wave owns 16 query rows)
__global__ __launch_bounds__(256) void attn_kernel(const __bf16* __restrict__ qb,
                                                   const __bf16* __restrict__ kb,
                                                   const __bf16* __restrict__ vtb,
                                                   __bf16* __restrict__ ab) {
    __shared__ __bf16 Pls[4][16 * 40];  // per-wave P tile [16 q][32 k], padded to 40
    const int bh = blockIdx.x >> 5;     // b*16 + h
    const int qt = blockIdx.x & 31;
    const int lane = threadIdx.x & 63, wid = threadIdx.x >> 6;
    const int q0w = qt * 64 + wid * 16;

    const __bf16* Qh = qb + (size_t)bh * 2048 * 64;
    const __bf16* Kh = kb + (size_t)bh * 2048 * 64;
    const __bf16* Vt = vtb + (size_t)bh * 64 * 2048;
    __bf16* Pw = &Pls[wid][0];

    // load Q fragments (16 rows x 64 d) once
    bf16x8 qf[2];
    {
        int qr = q0w + (lane & 15);
        const __bf16* qp = Qh + (size_t)qr * 64 + ((lane >> 4) << 3);
        qf[0] = ld_bf16x8(qp);
        qf[1] = ld_bf16x8(qp + 32);
    }

    f32x4 o[4];
    #pragma unroll
    for (int dt = 0; dt < 4; dt++) o[dt] = (f32x4){0.f, 0.f, 0.f, 0.f};
    float mrun[4] = {-1e30f, -1e30f, -1e30f, -1e30f};
    float srun[4] = {0.f, 0.f, 0.f, 0.f};

    const float scale = 0.125f;  // 1/sqrt(64)
    int klo = q0w - 255;
    int kt0 = klo > 0 ? (klo & ~31) : 0;

    for (int kt = kt0; kt <= q0w + 15; kt += 32) {
        // ---- scores for 32 keys (two 16-key subtiles) ----
        f32x4 s[2];
        #pragma unroll
        for (int kc = 0; kc < 2; kc++) {
            int krow = kt + kc * 16 + (lane & 15);
            const __bf16* kp = Kh + (size_t)krow * 64 + ((lane >> 4) << 3);
            bf16x8 kf0 = ld_bf16x8(kp);
            bf16x8 kf1 = ld_bf16x8(kp + 32);
            f32x4 a = (f32x4){0.f, 0.f, 0.f, 0.f};
            a = MFMA16(qf[0], kf0, a);
            a = MFMA16(qf[1], kf1, a);
            s[kc] = a;
        }
        // ---- joint online softmax over the 32 keys ----
        float p0v[4], p1v[4], factor[4];
        #pragma unroll
        for (int r = 0; r < 4; r++) {
            int q = q0w + ((lane >> 4) << 2) + r;
            int k0i = kt + (lane & 15);
            int k1i = k0i + 16;
            bool ok0 = (k0i <= q) && (k0i > q - 256);
            bool ok1 = (k1i <= q) && (k1i > q - 256);
            float s0 = ok0 ? s[0][r] * scale : -1e30f;
            float s1 = ok1 ? s[1][r] * scale : -1e30f;
            float mx = fmaxf(s0, s1);
            #pragma unroll
            for (int off = 1; off < 16; off <<= 1) mx = fmaxf(mx, __shfl_xor(mx, off));
            float mn = fmaxf(mrun[r], mx);
            float f = __expf(mrun[r] - mn);
            float p0 = ok0 ? __expf(s0 - mn) : 0.f;
            float p1 = ok1 ? __expf(s1 - mn) : 0.f;
            float ps = p0 + p1;
            #pragma unroll
            for (int off = 1; off < 16; off <<= 1) ps += __shfl_xor(ps, off);
            srun[r] = srun[r] * f + ps;
            mrun[r] = mn;
            factor[r] = f;
            p0v[r] = p0;
            p1v[r] = p1;
        }
        #pragma unroll
        for (int dt = 0; dt < 4; dt++) {
            #pragma unroll
            for (int r = 0; r < 4; r++) o[dt][r] *= factor[r];
        }
        // ---- write P (bf16) to per-wave LDS, [q][key] with pad 40 ----
        #pragma unroll
        for (int r = 0; r < 4; r++) {
            int qrow = ((lane >> 4) << 2) + r;
            Pw[qrow * 40 + (lane & 15)] = (__bf16)p0v[r];
            Pw[qrow * 40 + 16 + (lane & 15)] = (__bf16)p1v[r];
        }
        asm volatile("s_waitcnt lgkmcnt(0)" ::: "memory");
        // ---- PV: o(16x64) += P(16x32) * V(32x64), V from transposed buffer ----
        bf16x8 pf = ld_bf16x8(&Pw[(lane & 15) * 40 + ((lane >> 4) << 3)]);
        #pragma unroll
        for (int dt = 0; dt < 4; dt++) {
            bf16x8 vf = ld_bf16x8(&Vt[(size_t)(dt * 16 + (lane & 15)) * 2048 + kt + ((lane >> 4) << 3)]);
            o[dt] = MFMA16(pf, vf, o[dt]);
        }
    }

    // ---- normalize and store to a_buf [B*S][1024] at head offset ----
    const int bb = bh >> 4, hh = bh & 15;
    #pragma unroll
    for (int r = 0; r < 4; r++) {
        int q = q0w + ((lane >> 4) << 2) + r;
        float inv = 1.f / srun[r];
        size_t base = ((size_t)bb * 2048 + q) * 1024 + hh * 64;
        #pragma unroll
        for (int dt = 0; dt < 4; dt++) {
            ab[base + dt * 16 + (lane & 15)] = (__bf16)(o[dt][r] * inv);
        }
    }
}

// ---------------- launch ----------------
extern "C" void kernel_launch(void* const* d_in, const int* in_sizes, int n_in,
                              void* d_out, int out_size, void* d_ws, size_t ws_size,
                              hipStream_t stream) {
    const float* x = (const float*)d_in[0];       // [2,2048,1024]
    const float* w_attn = (const float*)d_in[1];  // [1024,3072]
    const float* b_attn = (const float*)d_in[2];  // [3072]
    const float* w_proj = (const float*)d_in[3];  // [1024,1024]
    const float* b_proj = (const float*)d_in[4];  // [1024]

    float* out = (float*)d_out;                      // [2,2048,1024]
    float* present = out + (size_t)2 * 2048 * 1024;  // [2,2,16,2048,64]

    char* w = (char*)d_ws;
    __bf16* xb   = (__bf16*)(w);                  // 8 MB (reused as a_buf)
    __bf16* wabt = (__bf16*)(w + 8388608);        // 6 MB  [3072][1024]
    __bf16* wpbt = (__bf16*)(w + 14680064);       // 2 MB  [1024][1024]
    __bf16* qb   = (__bf16*)(w + 16777216);       // 8 MB
    __bf16* kb   = (__bf16*)(w + 25165824);       // 8 MB
    __bf16* vt   = (__bf16*)(w + 33554432);       // 8 MB  [B*H][64][2048] transposed V
    __bf16* ab   = xb;  // a_buf reuses xb region (x consumed before attention writes)

    // converts + weight transposes
    cvt_kernel<<<2048, 256, 0, stream>>>(x, xb, 524288);
    tcvt_kernel<<<dim3(48, 16), 256, 0, stream>>>(w_attn, wabt, 1024, 3072);
    tcvt_kernel<<<dim3(16, 16), 256, 0, stream>>>(w_proj, wpbt, 1024, 1024);

    // QKV projection
    gemm_qkv_kernel<<<dim3(24, 32), 256, 0, stream>>>(xb, wabt, b_attn, qb, kb, vt, present);

    // attention
    attn_kernel<<<1024, 256, 0, stream>>>(qb, kb, vt, ab);

    // output projection
    gemm_proj_kernel<<<dim3(8, 32), 256, 0, stream>>>(ab, wpbt, b_proj, out);
}

// Round 4
// 124.000 us; speedup vs baseline: 1.1695x; 1.0415x over previous
//
#include <hip/hip_runtime.h>
#include <cstdint>
#include <cstddef>

typedef __bf16 bf16x8 __attribute__((ext_vector_type(8)));
typedef float f32x4 __attribute__((ext_vector_type(4)));

#define MFMA16(a, b, c) __builtin_amdgcn_mfma_f32_16x16x32_bf16(a, b, c, 0, 0, 0)

static __device__ __forceinline__ bf16x8 ld_bf16x8(const __bf16* p) {
    return *reinterpret_cast<const bf16x8*>(p);
}

static __device__ __forceinline__ void async_cp16(const __bf16* g, __bf16* l) {
    __builtin_amdgcn_global_load_lds((const __attribute__((address_space(1))) void*)g,
                                     (__attribute__((address_space(3))) void*)l, 16, 0, 0);
}

template <int N>
static __device__ __forceinline__ void wait_vmcnt() {
    asm volatile("s_waitcnt vmcnt(%0)" ::"n"(N) : "memory");
}

// ---------------- f32 -> bf16 convert (8 elems/thread) ----------------
__global__ void cvt_kernel(const float* __restrict__ src, __bf16* __restrict__ dst, int n8) {
    int i = blockIdx.x * blockDim.x + threadIdx.x;
    if (i >= n8) return;
    const float4* s4 = reinterpret_cast<const float4*>(src) + (size_t)i * 2;
    float4 a = s4[0], b = s4[1];
    bf16x8 o;
    o[0] = (__bf16)a.x; o[1] = (__bf16)a.y; o[2] = (__bf16)a.z; o[3] = (__bf16)a.w;
    o[4] = (__bf16)b.x; o[5] = (__bf16)b.y; o[6] = (__bf16)b.z; o[7] = (__bf16)b.w;
    reinterpret_cast<bf16x8*>(dst)[i] = o;
}

// ---------------- transpose-convert: in [K][N] f32 -> out [N][K] bf16, 64x64 tiles ----------------
__global__ __launch_bounds__(256) void tcvt_kernel(const float* __restrict__ in,
                                                   __bf16* __restrict__ out, int K, int N) {
    __shared__ __bf16 T[64][72];
    const int k0 = blockIdx.y * 64, n0 = blockIdx.x * 64;
    const int t = threadIdx.x;
    const int col = (t & 15) << 2;
    const int rowb = t >> 4;
    #pragma unroll
    for (int i = 0; i < 4; i++) {
        int row = i * 16 + rowb;
        float4 v = *reinterpret_cast<const float4*>(&in[(size_t)(k0 + row) * N + n0 + col]);
        T[col + 0][row] = (__bf16)v.x;
        T[col + 1][row] = (__bf16)v.y;
        T[col + 2][row] = (__bf16)v.z;
        T[col + 3][row] = (__bf16)v.w;
    }
    __syncthreads();
    const int oc = (t & 7) << 3;
    const int orb = t >> 3;
    #pragma unroll
    for (int i = 0; i < 2; i++) {
        int r = i * 32 + orb;
        bf16x8 v = *reinterpret_cast<bf16x8*>(&T[r][oc]);
        *reinterpret_cast<bf16x8*>(&out[(size_t)(n0 + r) * K + k0 + oc]) = v;
    }
}

// ---------------- deep-pipelined mainloop (8 waves, 3 LDS buffers, counted vmcnt) ----------
// C(BMxBN) += A(BMxK) * Bt(BNxK)^T, BK=32 per step, depth-2 prefetch.
// Schedule per iter t:  wait vmcnt(k)  -> tile t landed (t+1's k loads stay in flight)
//                       s_barrier      -> all waves: tile t landed, buf[(t+2)%3] free
//                       issue stage(t+2)
//                       ds_read frags(t); MFMA; lgkmcnt(0)
template <int BM, int BN, int WM, int WN>
__device__ __forceinline__ void mainloop2(const __bf16* __restrict__ A,
                                          const __bf16* __restrict__ Bt,
                                          int K, int row0, int col0,
                                          __bf16* lds,
                                          f32x4 (&acc)[BM / WM / 16][BN / WN / 16]) {
    constexpr int MR = BM / WM / 16, NR = BN / WN / 16;
    constexpr int AE = BM * 32;          // A elems per K-tile
    constexpr int BUFE = AE + BN * 32;   // elems per buffer
    constexpr int AI = BM / 16;          // 1024B stage-instructions for A
    constexpr int BI = BN / 16;
    constexpr int APW = AI / 8;          // A loads per wave per K-step
    constexpr int BPW = BI / 8;
    constexpr int BSPLIT = BI - BPW * 8; // first BSPLIT waves do one extra B load
    const int tid = threadIdx.x, l = tid & 63, w = tid >> 6;
    const int wm = w / WN, wn = w % WN;
    const int lr = l >> 2, lc = (l & 3) << 3;   // staging: row-sub, k-col
    const int fr = l & 15, fc = (l >> 4) << 3;  // fragment: row, k-offset

    const size_t arow = (size_t)(row0 + lr) * K + lc;
    const size_t brow = (size_t)(col0 + lr) * K + lc;
    const int nt = K >> 5;

    auto stage = [&](int t, int buf) {
        const int k0 = t << 5;
        const int bb = buf * BUFE;
        #pragma unroll
        for (int j = 0; j < APW; j++) {
            const int mi = w * APW + j;
            async_cp16(A + arow + (size_t)mi * 16 * K + k0, lds + bb + mi * 512 + l * 8);
        }
        if (BSPLIT == 0) {
            #pragma unroll
            for (int j = 0; j < BPW; j++) {
                const int ni = w * BPW + j;
                async_cp16(Bt + brow + (size_t)ni * 16 * K + k0, lds + bb + AE + ni * 512 + l * 8);
            }
        } else if (w < BSPLIT) {
            #pragma unroll
            for (int j = 0; j < BPW + 1; j++) {
                const int ni = w * (BPW + 1) + j;
                async_cp16(Bt + brow + (size_t)ni * 16 * K + k0, lds + bb + AE + ni * 512 + l * 8);
            }
        } else {
            #pragma unroll
            for (int j = 0; j < BPW; j++) {
                const int ni = BSPLIT * (BPW + 1) + (w - BSPLIT) * BPW + j;
                async_cp16(Bt + brow + (size_t)ni * 16 * K + k0, lds + bb + AE + ni * 512 + l * 8);
            }
        }
    };

    // prologue: two K-tiles in flight
    stage(0, 0);
    stage(1, 1);

    const int aoff = (wm * (BM / WM) + fr) * 32 + fc;
    const int boff = AE + (wn * (BN / WN) + fr) * 32 + fc;

    int p = 0;
    for (int t = 0; t < nt; ++t) {
        if (t + 1 < nt) {
            if (BSPLIT != 0 && w < BSPLIT) wait_vmcnt<APW + BPW + 1>();
            else wait_vmcnt<APW + BPW>();
        } else {
            wait_vmcnt<0>();
        }
        __builtin_amdgcn_sched_barrier(0);
        __builtin_amdgcn_s_barrier();
        __builtin_amdgcn_sched_barrier(0);
        if (t + 2 < nt) {
            int p2 = p + 2; if (p2 >= 3) p2 -= 3;
            stage(t + 2, p2);
        }
        const int cb = p * BUFE;
        bf16x8 af[MR], bfv[NR];
        #pragma unroll
        for (int m = 0; m < MR; m++) af[m] = ld_bf16x8(&lds[cb + aoff + m * 512]);
        #pragma unroll
        for (int n = 0; n < NR; n++) bfv[n] = ld_bf16x8(&lds[cb + boff + n * 512]);
        __builtin_amdgcn_s_setprio(1);
        #pragma unroll
        for (int m = 0; m < MR; m++) {
            #pragma unroll
            for (int n = 0; n < NR; n++) {
                acc[m][n] = MFMA16(af[m], bfv[n], acc[m][n]);
            }
        }
        __builtin_amdgcn_s_setprio(0);
        asm volatile("s_waitcnt lgkmcnt(0)" ::: "memory");  // reads of buf[p] complete before next barrier
        __builtin_amdgcn_sched_barrier(0);
        p = (p == 2) ? 0 : p + 1;
    }
}

// ---------------- QKV GEMM: x(4096x1024) @ w_attn^T(3072x1024) + b_attn, 256x192 tile ----------
__global__ __launch_bounds__(512, 2) void gemm_qkv_kernel(const __bf16* __restrict__ xb,
                                                          const __bf16* __restrict__ wabt,
                                                          const float* __restrict__ bias,
                                                          __bf16* __restrict__ qb,
                                                          __bf16* __restrict__ kb,
                                                          __bf16* __restrict__ vt,
                                                          float* __restrict__ present) {
    __shared__ __bf16 lds[3 * (256 * 32 + 192 * 32)];  // 84 KB
    f32x4 acc[8][3] = {};
    const int row0 = blockIdx.y * 256, col0 = blockIdx.x * 192;
    mainloop2<256, 192, 2, 4>(xb, wabt, 1024, row0, col0, lds, acc);

    const int lane = threadIdx.x & 63, w = threadIdx.x >> 6;
    const int wm = w >> 2, wn = w & 3;
    #pragma unroll
    for (int n = 0; n < 3; n++) {
        int col = col0 + wn * 48 + n * 16 + (lane & 15);
        int part = col >> 10;      // 0=q 1=k 2=v (per-col: 192-wide tiles span boundaries)
        int hh = (col >> 6) & 15;  // head
        int dd = col & 63;         // dim within head
        float bv = bias[col];
        #pragma unroll
        for (int m = 0; m < 8; m++) {
            #pragma unroll
            for (int r = 0; r < 4; r++) {
                int row = row0 + wm * 128 + m * 16 + ((lane >> 4) << 2) + r;
                int bb = row >> 11, ss = row & 2047;
                float val = acc[m][n][r] + bv;
                size_t qi = (((size_t)(bb * 16 + hh)) * 2048 + ss) * 64 + dd;
                if (part == 0) {
                    qb[qi] = (__bf16)val;
                } else if (part == 1) {
                    kb[qi] = (__bf16)val;
                    present[(((size_t)((bb * 2 + 0) * 16 + hh)) * 2048 + ss) * 64 + dd] = val;
                } else {
                    vt[(((size_t)(bb * 16 + hh)) * 64 + dd) * 2048 + ss] = (__bf16)val;
                    present[(((size_t)((bb * 2 + 1) * 16 + hh)) * 2048 + ss) * 64 + dd] = val;
                }
            }
        }
    }
}

// ---------------- Proj GEMM: a(4096x1024) @ w_proj^T(1024x1024) + b_proj, 128x128 tile ----------
__global__ __launch_bounds__(512, 2) void gemm_proj_kernel(const __bf16* __restrict__ ab,
                                                           const __bf16* __restrict__ wpbt,
                                                           const float* __restrict__ bias,
                                                           float* __restrict__ out) {
    __shared__ __bf16 lds[3 * (128 * 32 + 128 * 32)];  // 48 KB
    f32x4 acc[2][4] = {};
    const int row0 = blockIdx.y * 128, col0 = blockIdx.x * 128;
    mainloop2<128, 128, 4, 2>(ab, wpbt, 1024, row0, col0, lds, acc);

    const int lane = threadIdx.x & 63, w = threadIdx.x >> 6;
    const int wm = w >> 1, wn = w & 1;
    #pragma unroll
    for (int n = 0; n < 4; n++) {
        int col = col0 + wn * 64 + n * 16 + (lane & 15);
        float bv = bias[col];
        #pragma unroll
        for (int m = 0; m < 2; m++) {
            #pragma unroll
            for (int r = 0; r < 4; r++) {
                int row = row0 + wm * 32 + m * 16 + ((lane >> 4) << 2) + r;
                out[(size_t)row * 1024 + col] = acc[m][n][r] + bv;
            }
        }
    }
}

// ---------------- sliding-window causal flash attention ----------------
__global__ __launch_bounds__(256) void attn_kernel(const __bf16* __restrict__ qb,
                                                   const __bf16* __restrict__ kb,
                                                   const __bf16* __restrict__ vtb,
                                                   __bf16* __restrict__ ab) {
    __shared__ __bf16 Pls[4][16 * 40];
    const int bh = blockIdx.x >> 5;
    const int qt = blockIdx.x & 31;
    const int lane = threadIdx.x & 63, wid = threadIdx.x >> 6;
    const int q0w = qt * 64 + wid * 16;

    const __bf16* Qh = qb + (size_t)bh * 2048 * 64;
    const __bf16* Kh = kb + (size_t)bh * 2048 * 64;
    const __bf16* Vt = vtb + (size_t)bh * 64 * 2048;
    __bf16* Pw = &Pls[wid][0];

    bf16x8 qf[2];
    {
        int qr = q0w + (lane & 15);
        const __bf16* qp = Qh + (size_t)qr * 64 + ((lane >> 4) << 3);
        qf[0] = ld_bf16x8(qp);
        qf[1] = ld_bf16x8(qp + 32);
    }

    f32x4 o[4];
    #pragma unroll
    for (int dt = 0; dt < 4; dt++) o[dt] = (f32x4){0.f, 0.f, 0.f, 0.f};
    float mrun[4] = {-1e30f, -1e30f, -1e30f, -1e30f};
    float srun[4] = {0.f, 0.f, 0.f, 0.f};

    const float scale = 0.125f;
    int klo = q0w - 255;
    int kt0 = klo > 0 ? (klo & ~31) : 0;

    for (int kt = kt0; kt <= q0w + 15; kt += 32) {
        f32x4 s[2];
        #pragma unroll
        for (int kc = 0; kc < 2; kc++) {
            int krow = kt + kc * 16 + (lane & 15);
            const __bf16* kp = Kh + (size_t)krow * 64 + ((lane >> 4) << 3);
            bf16x8 kf0 = ld_bf16x8(kp);
            bf16x8 kf1 = ld_bf16x8(kp + 32);
            f32x4 a = (f32x4){0.f, 0.f, 0.f, 0.f};
            a = MFMA16(qf[0], kf0, a);
            a = MFMA16(qf[1], kf1, a);
            s[kc] = a;
        }
        float p0v[4], p1v[4], factor[4];
        #pragma unroll
        for (int r = 0; r < 4; r++) {
            int q = q0w + ((lane >> 4) << 2) + r;
            int k0i = kt + (lane & 15);
            int k1i = k0i + 16;
            bool ok0 = (k0i <= q) && (k0i > q - 256);
            bool ok1 = (k1i <= q) && (k1i > q - 256);
            float s0 = ok0 ? s[0][r] * scale : -1e30f;
            float s1 = ok1 ? s[1][r] * scale : -1e30f;
            float mx = fmaxf(s0, s1);
            #pragma unroll
            for (int off = 1; off < 16; off <<= 1) mx = fmaxf(mx, __shfl_xor(mx, off));
            float mn = fmaxf(mrun[r], mx);
            float f = __expf(mrun[r] - mn);
            float p0 = ok0 ? __expf(s0 - mn) : 0.f;
            float p1 = ok1 ? __expf(s1 - mn) : 0.f;
            float ps = p0 + p1;
            #pragma unroll
            for (int off = 1; off < 16; off <<= 1) ps += __shfl_xor(ps, off);
            srun[r] = srun[r] * f + ps;
            mrun[r] = mn;
            factor[r] = f;
            p0v[r] = p0;
            p1v[r] = p1;
        }
        #pragma unroll
        for (int dt = 0; dt < 4; dt++) {
            #pragma unroll
            for (int r = 0; r < 4; r++) o[dt][r] *= factor[r];
        }
        #pragma unroll
        for (int r = 0; r < 4; r++) {
            int qrow = ((lane >> 4) << 2) + r;
            Pw[qrow * 40 + (lane & 15)] = (__bf16)p0v[r];
            Pw[qrow * 40 + 16 + (lane & 15)] = (__bf16)p1v[r];
        }
        asm volatile("s_waitcnt lgkmcnt(0)" ::: "memory");
        bf16x8 pf = ld_bf16x8(&Pw[(lane & 15) * 40 + ((lane >> 4) << 3)]);
        #pragma unroll
        for (int dt = 0; dt < 4; dt++) {
            bf16x8 vf = ld_bf16x8(&Vt[(size_t)(dt * 16 + (lane & 15)) * 2048 + kt + ((lane >> 4) << 3)]);
            o[dt] = MFMA16(pf, vf, o[dt]);
        }
    }

    const int bb = bh >> 4, hh = bh & 15;
    #pragma unroll
    for (int r = 0; r < 4; r++) {
        int q = q0w + ((lane >> 4) << 2) + r;
        float inv = 1.f / srun[r];
        size_t base = ((size_t)bb * 2048 + q) * 1024 + hh * 64;
        #pragma unroll
        for (int dt = 0; dt < 4; dt++) {
            ab[base + dt * 16 + (lane & 15)] = (__bf16)(o[dt][r] * inv);
        }
    }
}

// ---------------- launch ----------------
extern "C" void kernel_launch(void* const* d_in, const int* in_sizes, int n_in,
                              void* d_out, int out_size, void* d_ws, size_t ws_size,
                              hipStream_t stream) {
    const float* x = (const float*)d_in[0];
    const float* w_attn = (const float*)d_in[1];
    const float* b_attn = (const float*)d_in[2];
    const float* w_proj = (const float*)d_in[3];
    const float* b_proj = (const float*)d_in[4];

    float* out = (float*)d_out;
    float* present = out + (size_t)2 * 2048 * 1024;

    char* w = (char*)d_ws;
    __bf16* xb   = (__bf16*)(w);
    __bf16* wabt = (__bf16*)(w + 8388608);
    __bf16* wpbt = (__bf16*)(w + 14680064);
    __bf16* qb   = (__bf16*)(w + 16777216);
    __bf16* kb   = (__bf16*)(w + 25165824);
    __bf16* vt   = (__bf16*)(w + 33554432);
    __bf16* ab   = xb;

    cvt_kernel<<<2048, 256, 0, stream>>>(x, xb, 524288);
    tcvt_kernel<<<dim3(48, 16), 256, 0, stream>>>(w_attn, wabt, 1024, 3072);
    tcvt_kernel<<<dim3(16, 16), 256, 0, stream>>>(w_proj, wpbt, 1024, 1024);

    gemm_qkv_kernel<<<dim3(16, 16), 512, 0, stream>>>(xb, wabt, b_attn, qb, kb, vt, present);

    attn_kernel<<<1024, 256, 0, stream>>>(qb, kb, vt, ab);

    gemm_proj_kernel<<<dim3(8, 32), 512, 0, stream>>>(ab, wpbt, b_proj, out);
}